// Round 4
// baseline (6857.970 us; speedup 1.0000x reference)
//
#include <hip/hip_runtime.h>

#define HDIM 2048
#define NL 2
#define NSTEPS 32
#define NACT 64
#define NBLK 256
#define TPB 512

typedef unsigned int u32;
typedef unsigned short u16;

// ---------------- threefry2x32 (exact JAX semantics) ----------------
__device__ __forceinline__ void tf2x32(u32 k0, u32 k1, u32 x0, u32 x1,
                                       u32& o0, u32& o1) {
  u32 ks0 = k0, ks1 = k1, ks2 = k0 ^ k1 ^ 0x1BD11BDAu;
  x0 += ks0; x1 += ks1;
#define TF_R(r) { x0 += x1; x1 = (x1 << (r)) | (x1 >> (32 - (r))); x1 ^= x0; }
  TF_R(13) TF_R(15) TF_R(26) TF_R(6)   x0 += ks1; x1 += ks2 + 1u;
  TF_R(17) TF_R(29) TF_R(16) TF_R(24)  x0 += ks2; x1 += ks0 + 2u;
  TF_R(13) TF_R(15) TF_R(26) TF_R(6)   x0 += ks0; x1 += ks1 + 3u;
  TF_R(17) TF_R(29) TF_R(16) TF_R(24)  x0 += ks1; x1 += ks2 + 4u;
  TF_R(13) TF_R(15) TF_R(26) TF_R(6)   x0 += ks2; x1 += ks0 + 5u;
#undef TF_R
  o0 = x0; o1 = x1;
}

__device__ __forceinline__ float bflo(u32 u) { return __uint_as_float(u << 16); }
__device__ __forceinline__ float bfhi(u32 u) { return __uint_as_float(u & 0xFFFF0000u); }

__device__ __forceinline__ u16 to_bf16(float f) {
  u32 u = __float_as_uint(f);
  u += 0x7FFFu + ((u >> 16) & 1u);   // round-to-nearest-even
  return (u16)(u >> 16);
}

struct Params {
  const float* start_token;  // [H]
  const float* action_emb;   // [NACT][H]
  const float* head_wT;      // [NSTEPS][H][NACT] transposed head
  const float* head_b;       // [NSTEPS][NACT]
  const u16*   wih;          // [NL][4H][H] bf16
  const u16*   whh;          // [NL][4H][H] bf16
  const float* bias;         // [NL][4H]  (b_ih + b_hh)
  float* hbuf;               // [2][NL][H] double-buffered h
  float* part;               // [NACT][NBLK] per-block head partials
  u32*   bar_cnt;            // grid barrier count
  u32*   bar_gen;            // grid barrier generation
  float* out;                // [NSTEPS+1]
};

// dot of one bf16 weight row (2048) with per-lane cached input slice.
// lane i owns elements j*512 + i*8 .. +8 for j in 0..3.
__device__ __forceinline__ float dot_row(const u16* __restrict__ wrow,
                                         const float* xr, int lane) {
  float acc = 0.f;
#pragma unroll
  for (int j = 0; j < 4; ++j) {
    uint4 wv = *reinterpret_cast<const uint4*>(wrow + j * 512 + lane * 8);
    acc = fmaf(bflo(wv.x), xr[j * 8 + 0], acc);
    acc = fmaf(bfhi(wv.x), xr[j * 8 + 1], acc);
    acc = fmaf(bflo(wv.y), xr[j * 8 + 2], acc);
    acc = fmaf(bfhi(wv.y), xr[j * 8 + 3], acc);
    acc = fmaf(bflo(wv.z), xr[j * 8 + 4], acc);
    acc = fmaf(bfhi(wv.z), xr[j * 8 + 5], acc);
    acc = fmaf(bflo(wv.w), xr[j * 8 + 6], acc);
    acc = fmaf(bfhi(wv.w), xr[j * 8 + 7], acc);
  }
  return acc;
}

__device__ __forceinline__ void load_vec(float* r, const float* __restrict__ v,
                                         int lane) {
#pragma unroll
  for (int j = 0; j < 4; ++j) {
    float4 a = *reinterpret_cast<const float4*>(v + j * 512 + lane * 8);
    float4 b = *reinterpret_cast<const float4*>(v + j * 512 + lane * 8 + 4);
    r[j * 8 + 0] = a.x; r[j * 8 + 1] = a.y; r[j * 8 + 2] = a.z; r[j * 8 + 3] = a.w;
    r[j * 8 + 4] = b.x; r[j * 8 + 5] = b.y; r[j * 8 + 6] = b.z; r[j * 8 + 7] = b.w;
  }
}

__device__ __forceinline__ float wave_sum(float v) {
#pragma unroll
  for (int off = 32; off > 0; off >>= 1) v += __shfl_xor(v, off);
  return v;
}

// ---- manual grid barrier: sense-reversing, agent scope, 256 co-resident blocks
__device__ __forceinline__ void gbar(u32* cnt, u32* gen) {
  __syncthreads();
  __threadfence();  // agent-scope release: publish this block's global writes
  if (threadIdx.x == 0) {
    u32 g = __hip_atomic_load(gen, __ATOMIC_RELAXED, __HIP_MEMORY_SCOPE_AGENT);
    u32 prev = __hip_atomic_fetch_add(cnt, 1u, __ATOMIC_ACQ_REL,
                                      __HIP_MEMORY_SCOPE_AGENT);
    if (prev == (u32)(NBLK - 1)) {
      __hip_atomic_store(cnt, 0u, __ATOMIC_RELAXED, __HIP_MEMORY_SCOPE_AGENT);
      __hip_atomic_store(gen, g + 1u, __ATOMIC_RELEASE,
                         __HIP_MEMORY_SCOPE_AGENT);
    } else {
      while (__hip_atomic_load(gen, __ATOMIC_ACQUIRE,
                               __HIP_MEMORY_SCOPE_AGENT) == g)
        __builtin_amdgcn_s_sleep(2);
    }
  }
  __syncthreads();
  __threadfence();  // agent-scope acquire: invalidate stale L1/L2 lines
}

__global__ void __launch_bounds__(TPB) lstm_main(Params p) {
  const int tid = threadIdx.x;
  const int lane = tid & 63;
  const int w = tid >> 6;        // wave 0..7
  const int m = w & 1;           // 0 -> w_ih side, 1 -> w_hh side
  const int pairc = w >> 1;      // 0..3 -> cells {2p, 2p+1} within block
  const int cell0 = blockIdx.x * 8;

  __shared__ float part[8][8];      // [wave][ci*4+gate]
  __shared__ float gates[8][4];     // [cell][gate]
  __shared__ float h1loc[8];        // layer-1 h for this block's cells
  __shared__ float lds_logits[NACT];

  const u16* Wl0 = (m == 0) ? p.wih : p.whh;
  const u16* Wl1 = Wl0 + (size_t)4 * HDIM * HDIM;
  const u16* rows0[8];
  const u16* rows1[8];
#pragma unroll
  for (int ci = 0; ci < 2; ++ci)
#pragma unroll
    for (int g = 0; g < 4; ++g) {
      const size_t r = (size_t)g * HDIM + cell0 + 2 * pairc + ci;
      rows0[ci * 4 + g] = Wl0 + r * HDIM;
      rows1[ci * 4 + g] = Wl1 + r * HDIM;
    }

  float b0v = 0.f, b1v = 0.f;
  if (tid < 32) {
    const int c = tid >> 2, g = tid & 3;
    b0v = p.bias[g * HDIM + cell0 + c];
    b1v = p.bias[4 * HDIM + g * HDIM + cell0 + c];
  }

  float c0 = 0.f, c1 = 0.f;  // cell state (meaningful for tid<8)
  float logp_sum = 0.f;
  int act = 0;
  float vr[32];

  for (int s = 0; s < NSTEPS; ++s) {
    const int pr = s & 1, pw = (s + 1) & 1;

    // ================= layer 0 =================
    {
      const float* vin =
          (m == 0)
              ? ((s == 0) ? p.start_token : p.action_emb + (size_t)act * HDIM)
              : p.hbuf + (size_t)(pr * NL + 0) * HDIM;
      load_vec(vr, vin, lane);
      float acc[8];
#pragma unroll
      for (int r = 0; r < 8; ++r) acc[r] = dot_row(rows0[r], vr, lane);
#pragma unroll
      for (int r = 0; r < 8; ++r) {
        float v = wave_sum(acc[r]);
        if (lane == 0) part[w][r] = v;
      }
      __syncthreads();
      if (tid < 32) {
        const int c = tid >> 2, g = tid & 3;
        const int w0 = (c >> 1) * 2, idx = (c & 1) * 4 + g;
        gates[c][g] = part[w0][idx] + part[w0 + 1][idx] + b0v;
      }
      __syncthreads();  // gates write (tid<32) -> read (tid<8)
      if (tid < 8) {
        float gi = 1.f / (1.f + expf(-gates[tid][0]));
        float gf = 1.f / (1.f + expf(-gates[tid][1]));
        float gg = tanhf(gates[tid][2]);
        float go = 1.f / (1.f + expf(-gates[tid][3]));
        c0 = gf * c0 + gi * gg;
        float h = go * tanhf(c0);
        p.hbuf[(size_t)(pw * NL + 0) * HDIM + cell0 + tid] = h;
      }
    }
    gbar(p.bar_cnt, p.bar_gen);  // h0(new) visible grid-wide

    // ================= layer 1 (+ head partial) =================
    {
      const float* vin = (m == 0) ? p.hbuf + (size_t)(pw * NL + 0) * HDIM
                                  : p.hbuf + (size_t)(pr * NL + 1) * HDIM;
      load_vec(vr, vin, lane);
      float acc[8];
#pragma unroll
      for (int r = 0; r < 8; ++r) acc[r] = dot_row(rows1[r], vr, lane);
#pragma unroll
      for (int r = 0; r < 8; ++r) {
        float v = wave_sum(acc[r]);
        if (lane == 0) part[w][r] = v;
      }
      __syncthreads();
      if (tid < 32) {
        const int c = tid >> 2, g = tid & 3;
        const int w0 = (c >> 1) * 2, idx = (c & 1) * 4 + g;
        gates[c][g] = part[w0][idx] + part[w0 + 1][idx] + b1v;
      }
      __syncthreads();  // gates write (tid<32) -> read (tid<8)
      if (tid < 8) {
        float gi = 1.f / (1.f + expf(-gates[tid][0]));
        float gf = 1.f / (1.f + expf(-gates[tid][1]));
        float gg = tanhf(gates[tid][2]);
        float go = 1.f / (1.f + expf(-gates[tid][3]));
        c1 = gf * c1 + gi * gg;
        float h = go * tanhf(c1);
        p.hbuf[(size_t)(pw * NL + 1) * HDIM + cell0 + tid] = h;
        h1loc[tid] = h;
      }
      __syncthreads();  // h1loc write (tid<8) -> read (wave 0)
      if (w == 0) {  // wave 0: lane == action; deterministic per-block partial
        const float* hwp =
            p.head_wT + ((size_t)s * HDIM + cell0) * NACT + lane;
        float a2 = 0.f;
#pragma unroll
        for (int c = 0; c < 8; ++c) a2 = fmaf(hwp[c * NACT], h1loc[c], a2);
        p.part[(size_t)lane * NBLK + blockIdx.x] = a2;
      }
    }
    gbar(p.bar_cnt, p.bar_gen);  // all 256 partials visible grid-wide

    // ================= deterministic logits reduce =================
    {
      const int a = tid >> 3, j = tid & 7;  // 8 threads per action
      const float* pb = p.part + (size_t)a * NBLK + j * 32;
      float sum = 0.f;
#pragma unroll
      for (int q = 0; q < 8; ++q) {
        float4 v = *reinterpret_cast<const float4*>(pb + q * 4);
        sum += v.x + v.y + v.z + v.w;
      }
      sum += __shfl_xor(sum, 1);
      sum += __shfl_xor(sum, 2);
      sum += __shfl_xor(sum, 4);
      if (j == 0) lds_logits[a] = sum;
    }
    __syncthreads();

    // ====== sampling (partitionable threefry, jax>=0.4.30 default) ======
    {
      float logit = lds_logits[lane] + p.head_b[s * NACT + lane];

      // keys[s] = foldlike split: both words of tf2x32(key=(0,42), x=(0,s))
      u32 kA, kB;
      tf2x32(0u, 42u, 0u, (u32)s, kA, kB);
      // random_bits (partitionable, 32-bit): bits[j] = y0 ^ y1, x=(0,j)
      u32 y0, y1;
      tf2x32(kA, kB, 0u, (u32)lane, y0, y1);
      u32 bits = y0 ^ y1;

      float uf = __uint_as_float(0x3f800000u | (bits >> 9)) - 1.0f;
      const float tiny = 1.17549435e-38f;
      float u = fmaxf(tiny, uf + tiny);
      float gum = -logf(-logf(u));

      float score = logit + gum;
      int bi = lane;
      float bs = score;
#pragma unroll
      for (int off = 32; off > 0; off >>= 1) {
        float os = __shfl_xor(bs, off);
        int oi = __shfl_xor(bi, off);
        if (os > bs || (os == bs && oi < bi)) { bs = os; bi = oi; }
      }
      float mx = logit;
#pragma unroll
      for (int off = 32; off > 0; off >>= 1) mx = fmaxf(mx, __shfl_xor(mx, off));
      float se = wave_sum(expf(logit - mx));
      float la = __shfl(logit, bi);
      logp_sum += la - mx - logf(se);
      act = bi;
      if (blockIdx.x == 0 && tid == 0) p.out[s] = (float)bi;
    }
    __syncthreads();  // lds_logits reused next step
  }
  if (blockIdx.x == 0 && tid == 0) p.out[NSTEPS] = logp_sum;
}

// -------- init: f32->bf16 weights, head transpose, combined bias, zeroing ----
__global__ void init_kernel(const float* __restrict__ wih,
                            const float* __restrict__ whh,
                            const float* __restrict__ bih,
                            const float* __restrict__ bhh,
                            const float* __restrict__ head_w,
                            u16* __restrict__ wih_bf, u16* __restrict__ whh_bf,
                            float* __restrict__ head_wT,
                            float* __restrict__ bias, float* __restrict__ hbuf,
                            u32* __restrict__ bar) {
  const size_t idx = (size_t)blockIdx.x * blockDim.x + threadIdx.x;
  const size_t stride = (size_t)gridDim.x * blockDim.x;
  const size_t n4 = (size_t)NL * 4 * HDIM * HDIM / 4;  // float4 count
  for (size_t k = idx; k < n4; k += stride) {
    float4 a = reinterpret_cast<const float4*>(wih)[k];
    float4 b = reinterpret_cast<const float4*>(whh)[k];
    ushort4 ua, ub;
    ua.x = to_bf16(a.x); ua.y = to_bf16(a.y);
    ua.z = to_bf16(a.z); ua.w = to_bf16(a.w);
    ub.x = to_bf16(b.x); ub.y = to_bf16(b.y);
    ub.z = to_bf16(b.z); ub.w = to_bf16(b.w);
    reinterpret_cast<ushort4*>(wih_bf)[k] = ua;
    reinterpret_cast<ushort4*>(whh_bf)[k] = ub;
  }
  // head_wT[s][h][a] = head_w[s][a][h]
  for (size_t k = idx; k < (size_t)NSTEPS * HDIM * NACT; k += stride) {
    const int a = (int)(k & (NACT - 1));
    const int h = (int)((k >> 6) & (HDIM - 1));
    const int s = (int)(k >> 17);
    head_wT[k] = head_w[((size_t)s * NACT + a) * HDIM + h];
  }
  for (size_t k = idx; k < (size_t)NL * 4 * HDIM; k += stride)
    bias[k] = bih[k] + bhh[k];
  for (size_t k = idx; k < (size_t)2 * NL * HDIM; k += stride) hbuf[k] = 0.f;
  if (idx < 2) bar[idx] = 0u;
}

extern "C" void kernel_launch(void* const* d_in, const int* in_sizes, int n_in,
                              void* d_out, int out_size, void* d_ws,
                              size_t ws_size, hipStream_t stream) {
  (void)in_sizes; (void)n_in; (void)out_size; (void)ws_size;
  const float* start_token = (const float*)d_in[0];
  const float* action_emb  = (const float*)d_in[1];
  const float* w_ih        = (const float*)d_in[2];
  const float* w_hh        = (const float*)d_in[3];
  const float* b_ih        = (const float*)d_in[4];
  const float* b_hh        = (const float*)d_in[5];
  const float* head_w      = (const float*)d_in[6];
  const float* head_b      = (const float*)d_in[7];

  char* ws = (char*)d_ws;
  const size_t WN = (size_t)NL * 4 * HDIM * HDIM;      // 33,554,432 elems
  u16* wih_bf    = (u16*)ws;                           // WN*2 bytes
  u16* whh_bf    = (u16*)(ws + WN * 2);                // WN*2 bytes
  size_t off     = WN * 4;
  float* head_wT = (float*)(ws + off); off += (size_t)NSTEPS * HDIM * NACT * 4;
  float* bias    = (float*)(ws + off); off += (size_t)NL * 4 * HDIM * 4;
  float* hbuf    = (float*)(ws + off); off += (size_t)2 * NL * HDIM * 4;
  float* partb   = (float*)(ws + off); off += (size_t)NACT * NBLK * 4;
  u32*   bar     = (u32*)(ws + off);

  init_kernel<<<dim3(2048), dim3(256), 0, stream>>>(
      w_ih, w_hh, b_ih, b_hh, head_w, wih_bf, whh_bf, head_wT, bias, hbuf,
      bar);

  Params p;
  p.start_token = start_token;
  p.action_emb = action_emb;
  p.head_wT = head_wT;
  p.head_b = head_b;
  p.wih = wih_bf;
  p.whh = whh_bf;
  p.bias = bias;
  p.hbuf = hbuf;
  p.part = partb;
  p.bar_cnt = bar;
  p.bar_gen = bar + 1;
  p.out = (float*)d_out;

  lstm_main<<<dim3(NBLK), dim3(TPB), 0, stream>>>(p);
}